// Round 8
// baseline (43641.022 us; speedup 1.0000x reference)
//
#include <hip/hip_runtime.h>
#include <cstdint>
#include <cstddef>

// B=256 batch, n=512 classes/steps, H=512 hidden, 3H=1536.
#define BB 256
#define NN 512
#define HH 512
#define G3 1536

typedef short bf16x8 __attribute__((ext_vector_type(8)));
typedef float f32x4 __attribute__((ext_vector_type(4)));

// ---------------- static device state ----------------
// Weight planes (hi then lo), MFMA fragment order. 1536-row weights use
// GATE-INTERLEAVED tiles: tile(c) = ((c&511)>>4)*3 + (c>>9); W_out: tile=c>>4.
// Fragment offset: (tile*16 + S)*512 + qu*128 + ci*8 + j.
__device__ __align__(16) short g_Whh0[2 * 786432];
__device__ __align__(16) short g_Whh1[2 * 786432];
__device__ __align__(16) short g_Wih1[2 * 786432];
__device__ __align__(16) short g_Wout[2 * 262144];
// h-state bf16 hi/lo planes, SINGLE buffered (phase analysis: no overlap);
// off(b,h) = (b>>4)*8192 + (h>>5)*512 + ((h>>3)&3)*128 + (b&15)*8 + (h&7)
__device__ __align__(16) short g_h0p[2 * 131072];
__device__ __align__(16) short g_h1p[2 * 131072];
__device__ __align__(16) float g_logits[BB * NN];  // preset to b_out, atomic-accumulated
__device__ __align__(16) float g_WihT[NN * G3];    // W_ih0^T (constant)
__device__ __align__(16) float g_ones[G3];         // gi0 at t=0 (incl b_ih0)
__device__ int g_idx[BB];
// barrier: per-mt 16 arrival slots (64B apart) + go flag. All RELAXED.
__device__ unsigned g_slot[16 * 256];
__device__ unsigned g_go[16 * 32];

// ---------------- sc1 (agent-scope relaxed) access ----------------
__device__ __forceinline__ unsigned long long cload_u64(const void* p) {
  return __hip_atomic_load((const unsigned long long*)p, __ATOMIC_RELAXED,
                           __HIP_MEMORY_SCOPE_AGENT);
}
__device__ __forceinline__ bf16x8 cload_frag(const short* p) {
  union { unsigned long long q[2]; bf16x8 v; } u;
  u.q[0] = cload_u64(p);
  u.q[1] = cload_u64(p + 4);
  return u.v;
}
__device__ __forceinline__ float cloadf(const float* p) {
  return __hip_atomic_load(p, __ATOMIC_RELAXED, __HIP_MEMORY_SCOPE_AGENT);
}
__device__ __forceinline__ void cstoref(float* p, float v) {
  __hip_atomic_store(p, v, __ATOMIC_RELAXED, __HIP_MEMORY_SCOPE_AGENT);
}
__device__ __forceinline__ void cstores(short* p, short v) {
  __hip_atomic_store((unsigned short*)p, (unsigned short)v, __ATOMIC_RELAXED,
                     __HIP_MEMORY_SCOPE_AGENT);
}

// ---------------- bf16 hi/lo helpers ----------------
__device__ __forceinline__ unsigned short bf16_rne(float f) {
  uint32_t u = __float_as_uint(f);
  uint32_t r = u + 0x7FFFu + ((u >> 16) & 1u);
  return (unsigned short)(r >> 16);
}
__device__ __forceinline__ float bf16_to_f(unsigned short h) {
  return __uint_as_float(((uint32_t)h) << 16);
}
__device__ __forceinline__ float sigf(float x) {
  return 1.0f / (1.0f + expf(-x));
}
__device__ __forceinline__ f32x4 mfma16(bf16x8 a, bf16x8 b, f32x4 c) {
  return __builtin_amdgcn_mfma_f32_16x16x32_bf16(a, b, c, 0, 0, 0);
}
__device__ __forceinline__ void store_h_plane(short* plane, int b, int h,
                                              float v) {
  int off = (b >> 4) * 8192 + (h >> 5) * 512 + ((h >> 3) & 3) * 128 +
            (b & 15) * 8 + (h & 7);
  unsigned short hi = bf16_rne(v);
  cstores(plane + off, (short)hi);
  cstores(plane + 131072 + off, (short)bf16_rne(v - bf16_to_f(hi)));
}

// ---------------- threefry2x32 (JAX-exact, 20 rounds) ----------------
__device__ __forceinline__ uint32_t rotl32(uint32_t v, int r) {
  return (v << r) | (v >> (32 - r));
}
__device__ __forceinline__ void threefry2x32(uint32_t k0, uint32_t k1,
                                             uint32_t x0, uint32_t x1,
                                             uint32_t& o0, uint32_t& o1) {
  uint32_t k2 = k0 ^ k1 ^ 0x1BD11BDAu;
  x0 += k0; x1 += k1;
  x0 += x1; x1 = rotl32(x1, 13); x1 ^= x0;
  x0 += x1; x1 = rotl32(x1, 15); x1 ^= x0;
  x0 += x1; x1 = rotl32(x1, 26); x1 ^= x0;
  x0 += x1; x1 = rotl32(x1, 6);  x1 ^= x0;
  x0 += k1; x1 += k2 + 1u;
  x0 += x1; x1 = rotl32(x1, 17); x1 ^= x0;
  x0 += x1; x1 = rotl32(x1, 29); x1 ^= x0;
  x0 += x1; x1 = rotl32(x1, 16); x1 ^= x0;
  x0 += x1; x1 = rotl32(x1, 24); x1 ^= x0;
  x0 += k2; x1 += k0 + 2u;
  x0 += x1; x1 = rotl32(x1, 13); x1 ^= x0;
  x0 += x1; x1 = rotl32(x1, 15); x1 ^= x0;
  x0 += x1; x1 = rotl32(x1, 26); x1 ^= x0;
  x0 += x1; x1 = rotl32(x1, 6);  x1 ^= x0;
  x0 += k0; x1 += k1 + 3u;
  x0 += x1; x1 = rotl32(x1, 17); x1 ^= x0;
  x0 += x1; x1 = rotl32(x1, 29); x1 ^= x0;
  x0 += x1; x1 = rotl32(x1, 16); x1 ^= x0;
  x0 += x1; x1 = rotl32(x1, 24); x1 ^= x0;
  x0 += k1; x1 += k2 + 4u;
  x0 += x1; x1 = rotl32(x1, 13); x1 ^= x0;
  x0 += x1; x1 = rotl32(x1, 15); x1 ^= x0;
  x0 += x1; x1 = rotl32(x1, 26); x1 ^= x0;
  x0 += x1; x1 = rotl32(x1, 6);  x1 ^= x0;
  x0 += k2; x1 += k0 + 5u;
  o0 = x0; o1 = x1;
}
__device__ __forceinline__ float gumbel_from_bits(uint32_t bits) {
  float u = __uint_as_float((bits >> 9) | 0x3f800000u) - 1.0f;
  if (u == 0.0f) u = 1.17549435e-38f;
  return -logf(-logf(u));
}

// ---------------- prelude kernels ----------------
__global__ __launch_bounds__(256) void init_state_kernel() {
  int i = blockIdx.x * 256 + threadIdx.x;  // 1024 blocks
  if (i < 131072) {
    ((uint32_t*)g_h0p)[i] = 0u;
    ((uint32_t*)g_h1p)[i] = 0u;
  }
  if (i < 16 * 256) g_slot[i] = 0u;
  if (i < 16 * 32) g_go[i] = 0u;
  if (i < BB) g_idx[i] = 0;
}

__global__ __launch_bounds__(256) void ones_row_kernel(
    const float* __restrict__ W_ih0, const float* __restrict__ b_ih0) {
  int j = blockIdx.x * 256 + threadIdx.x;
  if (j < G3) {
    const float* row = W_ih0 + (size_t)j * NN;
    float s = 0.0f;
    for (int k = 0; k < NN; ++k) s += row[k];
    g_ones[j] = s + b_ih0[j];
  }
}

__global__ __launch_bounds__(256) void transpose_kernel(
    const float* __restrict__ in) {
  __shared__ float tile[32][33];
  int bx = blockIdx.x, by = blockIdx.y;
  int tx = threadIdx.x & 31, ty = threadIdx.x >> 5;
  for (int i = 0; i < 32; i += 8)
    tile[ty + i][tx] = in[(size_t)(by * 32 + ty + i) * NN + bx * 32 + tx];
  __syncthreads();
  for (int i = 0; i < 32; i += 8)
    g_WihT[(size_t)(bx * 32 + ty + i) * G3 + by * 32 + tx] = tile[tx][ty + i];
}

__global__ __launch_bounds__(256) void split_kernel(
    const float* __restrict__ W, short* __restrict__ dst, int rows,
    int plane) {
  int i = blockIdx.x * 256 + threadIdx.x;
  if (i >= rows * 64) return;
  int c = i >> 6, jb = i & 63, ci = c & 15;
  int tile = (rows == G3) ? (((c & 511) >> 4) * 3 + (c >> 9)) : (c >> 4);
  int S = jb >> 2, qu = jb & 3;
  int off = (tile * 16 + S) * 512 + qu * 128 + ci * 8;
  const float* src = W + (size_t)c * 512 + jb * 8;
  float v[8];
  *(float4*)v = *(const float4*)src;
  *(float4*)(v + 4) = *(const float4*)(src + 4);
  short hb[8], lb[8];
#pragma unroll
  for (int e = 0; e < 8; ++e) {
    unsigned short h = bf16_rne(v[e]);
    hb[e] = (short)h;
    lb[e] = (short)bf16_rne(v[e] - bf16_to_f(h));
  }
  *(bf16x8*)(dst + off) = *(const bf16x8*)hb;
  *(bf16x8*)(dst + plane + off) = *(const bf16x8*)lb;
}

// ---------------- relaxed mt-local barrier (no release/acquire cache ops) --
// Arrivals: per-block slots (distinct cachelines, relaxed store — the
// s_waitcnt vmcnt(0) emitted by the preceding __syncthreads drains all the
// block's sc1 data stores first; slot reaches LLC after them).
// Leader (nb==0) polls all 16 slots, publishes go; others poll go.
__device__ __forceinline__ void gbar(int mt, int nb, unsigned ep) {
  __syncthreads();
  if (threadIdx.x == 0) {
    asm volatile("s_waitcnt vmcnt(0)" ::: "memory");
    __hip_atomic_store(&g_slot[mt * 256 + nb * 16], ep, __ATOMIC_RELAXED,
                       __HIP_MEMORY_SCOPE_AGENT);
  }
  if (nb == 0) {
    if (threadIdx.x < 16) {
      while (__hip_atomic_load(&g_slot[mt * 256 + threadIdx.x * 16],
                               __ATOMIC_RELAXED,
                               __HIP_MEMORY_SCOPE_AGENT) < ep)
        __builtin_amdgcn_s_sleep(1);
    }
    __syncthreads();
    if (threadIdx.x == 0)
      __hip_atomic_store(&g_go[mt * 32], ep, __ATOMIC_RELAXED,
                         __HIP_MEMORY_SCOPE_AGENT);
  } else {
    if (threadIdx.x == 0) {
      while (__hip_atomic_load(&g_go[mt * 32], __ATOMIC_RELAXED,
                               __HIP_MEMORY_SCOPE_AGENT) < ep)
        __builtin_amdgcn_s_sleep(1);
    }
  }
  asm volatile("" ::: "memory");
  __syncthreads();
}

// ---------------- fragment GEMM: A (sc1) x W (plain cached) ----------------
// 3 gate-tiles for unit u; acc accumulated from zero by caller-init.
__device__ __forceinline__ void gemm3(const short* __restrict__ Ap,
                                      const short* __restrict__ Wp, int wplane,
                                      int mt, int u, int lnoff, f32x4* acc) {
#pragma unroll
  for (int S = 0; S < 16; ++S) {
    const int aoff = mt * 8192 + S * 512 + lnoff;
    bf16x8 ah = cload_frag(Ap + aoff);
    bf16x8 al = cload_frag(Ap + 131072 + aoff);
#pragma unroll
    for (int g = 0; g < 3; ++g) {
      const short* wp = Wp + ((u * 3 + g) * 16 + S) * 512 + lnoff;
      bf16x8 bh = *(const bf16x8*)wp;
      bf16x8 bl = *(const bf16x8*)(wp + wplane);
      acc[g] = mfma16(ah, bh, acc[g]);
      acc[g] = mfma16(ah, bl, acc[g]);
      acc[g] = mfma16(al, bh, acc[g]);
    }
  }
}

// ---------------- persistent kernel ----------------
// bid = mt*16 + nb. L-blocks nb<8 (u = nb*4+w): layer0 + gh0 prefetch +
// (nb==0) sampler. U-blocks nb>=8 (ku=nb-8, u=ku*4+w): layer1 + partial
// logits + gh1 prefetch. XCD = bid%8 = nb&7: weight slices L2-resident.
// Step: P2 cell0-epilogue -> beta -> P3 {U: gi1+cell1+logits | L: gh0(t+1)}
// -> gamma -> P4 {U: gh1(t+1) | nb==0: sampler} -> alpha.
__global__ __launch_bounds__(256) void persist_kernel(
    const float* __restrict__ b_ih0, const float* __restrict__ b_hh0,
    const float* __restrict__ b_ih1, const float* __restrict__ b_hh1,
    const float* __restrict__ b_out, float* __restrict__ out_perm,
    float* __restrict__ out_lp) {
  const int bid = blockIdx.x;
  const int mt = bid >> 4, nb = bid & 15;
  const int tid = threadIdx.x;
  const int w = tid >> 6, ln = tid & 63;
  const int ci = ln & 15, qu = ln >> 4;
  const int lnoff = ln * 8;
  const bool isL = (nb < 8);
  const int ku = nb - 8;
  const int u = (isL ? nb : ku) * 4 + w;
  const int h = u * 16 + ci;

  __shared__ short Lh[1024], Ll[1024];
  __shared__ float sred[512];
  __shared__ int sidx[256];
  __shared__ unsigned savail[16][16];
  __shared__ float slp[16];

  if (nb == 0) {
    if (tid < 16) slp[tid] = 0.0f;
    for (int i = tid; i < 256; i += 256) savail[i >> 4][i & 15] = 0xFFFFFFFFu;
  }
  __syncthreads();

  f32x4 z = (f32x4){0.f, 0.f, 0.f, 0.f};
  f32x4 accR[3] = {z, z, z};  // L: gh0(t) carried; U: gh1(t) carried
  float hprev[4] = {0.f, 0.f, 0.f, 0.f};

  for (int t = 0; t < NN; ++t) {
    // ================ P2: L: cell0 epilogue + logits preset ================
    if (isL) {
      const float br = b_hh0[h], bz = b_hh0[HH + h], bn = b_hh0[2 * HH + h];
      const float bi0 = b_ih0[h], bi1 = b_ih0[HH + h], bi2 = b_ih0[2 * HH + h];
#pragma unroll
      for (int r = 0; r < 4; ++r) {
        const int b = mt * 16 + qu * 4 + r;
        float ir, iz, in_;
        if (t == 0) {
          ir = g_ones[h]; iz = g_ones[HH + h]; in_ = g_ones[2 * HH + h];
        } else {
          int iv = __hip_atomic_load(&g_idx[b], __ATOMIC_RELAXED,
                                     __HIP_MEMORY_SCOPE_AGENT);
          const float* wr_ = g_WihT + (size_t)iv * G3;
          ir = wr_[h] + bi0;
          iz = wr_[HH + h] + bi1;
          in_ = wr_[2 * HH + h] + bi2;
        }
        float rr_ = sigf(ir + accR[0][r] + br);
        float zz = sigf(iz + accR[1][r] + bz);
        float ng = tanhf(in_ + rr_ * (accR[2][r] + bn));
        float hn = (1.f - zz) * ng + zz * hprev[r];
        hprev[r] = hn;
        store_h_plane(g_h0p, b, h, hn);
      }
      // preset logits slice [mt rows][nb*64 .. +64) = b_out (sampler(t-1)
      // finished: alpha barrier passed)
#pragma unroll
      for (int it = 0; it < 4; ++it) {
        int i = tid + it * 256;
        int r = i >> 6, c = i & 63;
        cstoref(&g_logits[(mt * 16 + r) * NN + nb * 64 + c],
                b_out[nb * 64 + c]);
      }
    }
    gbar(mt, nb, 3u * t + 1u);

    // ================ P3: U: gi1+cell1+partial logits | L: gh0(t+1) ========
    if (!isL) {
      f32x4 gi[3] = {z, z, z};
      gemm3(g_h0p, g_Wih1, 786432, mt, u, lnoff, gi);
      const float bi0 = b_ih1[h], bi1 = b_ih1[HH + h], bi2 = b_ih1[2 * HH + h];
      const float c0 = b_hh1[h], c1 = b_hh1[HH + h], c2 = b_hh1[2 * HH + h];
      float hn1[4];
#pragma unroll
      for (int r = 0; r < 4; ++r) {
        const int b = mt * 16 + qu * 4 + r;
        float rr_ = sigf(gi[0][r] + bi0 + accR[0][r] + c0);
        float zz = sigf(gi[1][r] + bi1 + accR[1][r] + c1);
        float ng = tanhf(gi[2][r] + bi2 + rr_ * (accR[2][r] + c2));
        float hn = (1.f - zz) * ng + zz * hprev[r];
        hprev[r] = hn;
        hn1[r] = hn;
        store_h_plane(g_h1p, b, h, hn);
      }
      // transpose own 16x64 h1' slice to A-fragment LDS (block k = w*16+ci)
      const int kk = w * 16 + ci;
#pragma unroll
      for (int r = 0; r < 4; ++r) {
        const int m = qu * 4 + r;
        const int off =
            (kk >> 5) * 512 + ((kk >> 3) & 3) * 128 + m * 8 + (kk & 7);
        unsigned short hi = bf16_rne(hn1[r]);
        Lh[off] = (short)hi;
        Ll[off] = (short)bf16_rne(hn1[r] - bf16_to_f(hi));
      }
      __syncthreads();
      f32x4 acc2[8] = {z, z, z, z, z, z, z, z};
#pragma unroll
      for (int S2 = 0; S2 < 2; ++S2) {
        bf16x8 ah = *(const bf16x8*)&Lh[S2 * 512 + lnoff];
        bf16x8 al = *(const bf16x8*)&Ll[S2 * 512 + lnoff];
#pragma unroll
        for (int j = 0; j < 8; ++j) {
          const int nt = w * 8 + j;
          const short* wp = g_Wout + (nt * 16 + ku * 2 + S2) * 512 + lnoff;
          bf16x8 bh = *(const bf16x8*)wp;
          bf16x8 bl = *(const bf16x8*)(wp + 262144);
          acc2[j] = mfma16(ah, bh, acc2[j]);
          acc2[j] = mfma16(ah, bl, acc2[j]);
          acc2[j] = mfma16(al, bh, acc2[j]);
        }
      }
#pragma unroll
      for (int j = 0; j < 8; ++j) {
        const int n = (w * 8 + j) * 16 + ci;
#pragma unroll
        for (int r = 0; r < 4; ++r) {
          const int b = mt * 16 + qu * 4 + r;
          __hip_atomic_fetch_add(&g_logits[b * NN + n], acc2[j][r],
                                 __ATOMIC_RELAXED, __HIP_MEMORY_SCOPE_AGENT);
        }
      }
    } else if (t < NN - 1) {
      accR[0] = z; accR[1] = z; accR[2] = z;
      gemm3(g_h0p, g_Whh0, 786432, mt, u, lnoff, accR);  // gh0(t+1)
    }
    gbar(mt, nb, 3u * t + 2u);

    // ================ P4: U: gh1(t+1) | nb==0: sampler ================
    if (!isL) {
      if (t < NN - 1) {
        accR[0] = z; accR[1] = z; accR[2] = z;
        gemm3(g_h1p, g_Whh1, 786432, mt, u, lnoff, accR);  // gh1(t+1)
      }
    } else if (nb == 0) {
      const int r = tid >> 4, l16 = tid & 15;
      const int b = mt * 16 + r;
      uint32_t tp = (uint32_t)(t & 255);
      uint32_t a0, a1, c0k, c1k;
      threefry2x32(0u, 42u, 2u * tp, 2u * tp + 512u, a0, a1);
      threefry2x32(0u, 42u, 2u * tp + 1u, 2u * tp + 1u + 512u, c0k, c1k);
      uint32_t sk0 = (t < 256) ? a0 : a1;
      uint32_t sk1 = (t < 256) ? c0k : c1k;

      float best = -1.0f / 0.0f;
      int bi = 0;
      float sum = 0.0f;
#pragma unroll 4
      for (int k = 0; k < 32; ++k) {
        int c = l16 + k * 16;
        uint32_t cnt = (uint32_t)(b & 127) * 512u + (uint32_t)c;
        uint32_t r0, r1;
        threefry2x32(sk0, sk1, cnt, cnt + 65536u, r0, r1);
        float g = gumbel_from_bits((b < 128) ? r0 : r1);
        float l = cloadf(&g_logits[b * NN + c]);
        bool av = (savail[r][c >> 5] >> (c & 31)) & 1u;
        float ml = av ? l : -1.0e9f;
        float v = g + ml;
        if (v > best || (v == best && c < bi)) { best = v; bi = c; }
        sum += av ? expf(l) : 0.0f;
      }
      sred[tid] = best; sidx[tid] = bi; sred[256 + tid] = sum;
      __syncthreads();
      for (int s = 8; s > 0; s >>= 1) {
        if (l16 < s) {
          float v2 = sred[tid + s]; int i2 = sidx[tid + s];
          if (v2 > sred[tid] || (v2 == sred[tid] && i2 < sidx[tid])) {
            sred[tid] = v2; sidx[tid] = i2;
          }
          sred[256 + tid] += sred[256 + tid + s];
        }
        __syncthreads();
      }
      const int sel = sidx[r * 16];
      if (l16 == 0) {
        float ssum = sred[256 + r * 16];
        float lsel = cloadf(&g_logits[b * NN + sel]);
        float pz = expf(lsel) / ssum;
        slp[r] += logf(pz + 1e-9f);
        savail[r][sel >> 5] &= ~(1u << (sel & 31));
        __hip_atomic_store(&g_idx[b], sel, __ATOMIC_RELAXED,
                           __HIP_MEMORY_SCOPE_AGENT);
        out_perm[(size_t)b * NN * NN + (size_t)t * NN + sel] = 1.0f;
        if (t == NN - 1) out_lp[b] = slp[r];
      }
      __syncthreads();
    }
    gbar(mt, nb, 3u * t + 3u);
  }
}

// ---------------- host ----------------
extern "C" void kernel_launch(void* const* d_in, const int* in_sizes, int n_in,
                              void* d_out, int out_size, void* d_ws,
                              size_t ws_size, hipStream_t stream) {
  (void)in_sizes; (void)n_in; (void)d_ws; (void)ws_size;
  const float* W_ih0 = (const float*)d_in[1];
  const float* W_hh0 = (const float*)d_in[2];
  const float* b_ih0 = (const float*)d_in[3];
  const float* b_hh0 = (const float*)d_in[4];
  const float* W_ih1 = (const float*)d_in[5];
  const float* W_hh1 = (const float*)d_in[6];
  const float* b_ih1 = (const float*)d_in[7];
  const float* b_hh1 = (const float*)d_in[8];
  const float* W_out = (const float*)d_in[9];
  const float* b_out = (const float*)d_in[10];

  float* out = (float*)d_out;
  float* out_lp = out + (size_t)BB * NN * NN;

  hipMemsetAsync(d_out, 0, (size_t)out_size * sizeof(float), stream);
  init_state_kernel<<<1024, 256, 0, stream>>>();
  ones_row_kernel<<<6, 256, 0, stream>>>(W_ih0, b_ih0);
  transpose_kernel<<<dim3(16, 48), 256, 0, stream>>>(W_ih0);

  short* whh0; hipGetSymbolAddress((void**)&whh0, HIP_SYMBOL(g_Whh0));
  short* whh1; hipGetSymbolAddress((void**)&whh1, HIP_SYMBOL(g_Whh1));
  short* wih1; hipGetSymbolAddress((void**)&wih1, HIP_SYMBOL(g_Wih1));
  short* wout; hipGetSymbolAddress((void**)&wout, HIP_SYMBOL(g_Wout));
  split_kernel<<<384, 256, 0, stream>>>(W_hh0, whh0, G3, 786432);
  split_kernel<<<384, 256, 0, stream>>>(W_hh1, whh1, G3, 786432);
  split_kernel<<<384, 256, 0, stream>>>(W_ih1, wih1, G3, 786432);
  split_kernel<<<128, 256, 0, stream>>>(W_out, wout, NN, 262144);

  persist_kernel<<<256, 256, 0, stream>>>(b_ih0, b_hh0, b_ih1, b_hh1, b_out,
                                          out, out_lp);
}